// Round 1
// 157.193 us; speedup vs baseline: 1.0070x; 1.0070x over previous
//
#include <hip/hip_runtime.h>

#define VOCAB 100000
#define EMBED 128
#define MAX_PATH 20
#define BATCH 32768
#define WPB 4                    // waves per block (block = 256 threads)
#define NBLOCKS (BATCH / WPB)    // 8192

// R9: occupancy push. R8 was latency-bound (hbm 38%, VALU 26%, occ 52%),
// limited by LDS: 3 staged chunks x 2KB x 4 waves = 24.5 KB/block -> 6
// blocks/CU = 24 waves/CU. Move chunk 2 to register staging (+8 VGPR,
// budget was 40/64) -> LDS = 2 chunks/wave = 16.4 KB/block -> 8 blocks/CU
// = 32 waves/CU (HW max), declared via __launch_bounds__(256, 8).
//  - chunks 0,1,2 -> register gathers (issue before LDS stages; even if
//    the compiler sinks chunk 2, it still issues before the vmcnt(0)
//    drain, and the drain itself moves later -> more slack for stages)
//  - chunks 3,4 -> global_load_lds (conditional, wave-uniform ballot skip)
//  - per-wave s_waitcnt vmcnt(0) instead of __syncthreads (private regions)
// Layout: every vmem instr is 256B-contiguous per 16-lane group; LDS stage
// obeys dest = uniform base + lane*16 (m104/m108), readback contiguous.
__global__ __launch_bounds__(256, 8) void hs_loss_kernel(
    const int* __restrict__ center, const int* __restrict__ target,
    const float* __restrict__ in_emb, const float* __restrict__ inner_vec,
    const int* __restrict__ paths, const float* __restrict__ codes,
    float* __restrict__ partials)
{
    __shared__ float4 lds_buf[WPB * 256];   // 2 chunks x 2 KB per wave = 16 KB
    __shared__ float  ws[WPB];

    const int wave = threadIdx.x >> 6;
    const int lane = threadIdx.x & 63;
    const int g    = lane >> 4;   // group 0..3
    const int gl   = lane & 15;   // lane within group
    const int b = blockIdx.x * WPB + wave;

    const int c = center[b];
    const int t = target[b];

    // h fragment (reused 5x): 256B-contiguous per instruction
    const float4* hp = (const float4*)(in_emb + (size_t)c * EMBED);
    const float4 h0 = hp[gl];
    const float4 h1 = hp[gl + 16];

    // Group g's 5 (path, code) pairs: nodes g, g+4, ..., g+16
    const int base = t * MAX_PATH + g;
    int   p[5];
    float cd[5];
    #pragma unroll
    for (int j = 0; j < 5; ++j) {
        p[j]  = paths[base + 4 * j];
        cd[j] = codes[base + 4 * j];
    }
    // wave-uniform chunk validity (all 4 groups share one path length)
    const bool do3 = __ballot(cd[3] != 0.f) != 0ull;
    const bool do4 = __ballot(cd[4] != 0.f) != 0ull;

    // register gathers: chunks 0,1,2
    const float4* v0 = (const float4*)(inner_vec + (size_t)p[0] * EMBED);
    const float4 r00 = v0[gl], r01 = v0[gl + 16];
    const float4* v1 = (const float4*)(inner_vec + (size_t)p[1] * EMBED);
    const float4 r10 = v1[gl], r11 = v1[gl + 16];
    const float4* v2 = (const float4*)(inner_vec + (size_t)p[2] * EMBED);
    const float4 r20 = v2[gl], r21 = v2[gl + 16];

    // async LDS stages: chunks 3,4 (two 1024B instrs each)
    float4* myl = lds_buf + wave * 256;
    if (do3) {
        const float* src = inner_vec + (size_t)p[3] * EMBED + 4 * gl;
        __builtin_amdgcn_global_load_lds(
            (const __attribute__((address_space(1))) unsigned int*)(src),
            (__attribute__((address_space(3))) unsigned int*)(myl),
            16, 0, 0);
        __builtin_amdgcn_global_load_lds(
            (const __attribute__((address_space(1))) unsigned int*)(src + 64),
            (__attribute__((address_space(3))) unsigned int*)(myl + 64),
            16, 0, 0);
    }
    if (do4) {
        const float* src = inner_vec + (size_t)p[4] * EMBED + 4 * gl;
        __builtin_amdgcn_global_load_lds(
            (const __attribute__((address_space(1))) unsigned int*)(src),
            (__attribute__((address_space(3))) unsigned int*)(myl + 128),
            16, 0, 0);
        __builtin_amdgcn_global_load_lds(
            (const __attribute__((address_space(1))) unsigned int*)(src + 64),
            (__attribute__((address_space(3))) unsigned int*)(myl + 192),
            16, 0, 0);
    }

    float acc = 0.f;
    // ---- chunks 0,1,2 from registers (compiler inserts partial vmcnt waits)
    #pragma unroll
    for (int j = 0; j < 3; ++j) {
        const float4 a0 = (j == 0) ? r00 : (j == 1) ? r10 : r20;
        const float4 a1 = (j == 0) ? r01 : (j == 1) ? r11 : r21;
        float d = h0.x * a0.x;
        d = fmaf(h0.y, a0.y, d);
        d = fmaf(h0.z, a0.z, d);
        d = fmaf(h0.w, a0.w, d);
        float e = h1.x * a1.x;
        e = fmaf(h1.y, a1.y, e);
        e = fmaf(h1.z, a1.z, e);
        e = fmaf(h1.w, a1.w, e);
        d += e;
        d += __shfl_xor(d, 1, 64);
        d += __shfl_xor(d, 2, 64);
        d += __shfl_xor(d, 4, 64);
        d += __shfl_xor(d, 8, 64);
        const float x  = cd[j] * d;
        const float ls = fminf(x, 0.f) - __logf(1.f + __expf(-fabsf(x)));
        acc = fmaf(fabsf(cd[j]), ls, acc);
    }

    // ---- per-wave drain of my LDS stages (NOT a block barrier)
    __builtin_amdgcn_s_waitcnt(0xF70);      // vmcnt(0), lgkm/exp unconstrained
    __builtin_amdgcn_sched_barrier(0);      // pin: no ds_read hoisted above

    // ---- chunks 3,4 from LDS (contiguous ds_read_b128, conflict-free)
    #pragma unroll
    for (int j = 3; j < 5; ++j) {
        if (j == 3 && !do3) continue;       // wave-uniform skip (LDS garbage)
        if (j == 4 && !do4) continue;
        const float4 a0 = myl[(j - 3) * 128 + lane];
        const float4 a1 = myl[(j - 3) * 128 + 64 + lane];
        float d = h0.x * a0.x;
        d = fmaf(h0.y, a0.y, d);
        d = fmaf(h0.z, a0.z, d);
        d = fmaf(h0.w, a0.w, d);
        float e = h1.x * a1.x;
        e = fmaf(h1.y, a1.y, e);
        e = fmaf(h1.z, a1.z, e);
        e = fmaf(h1.w, a1.w, e);
        d += e;
        d += __shfl_xor(d, 1, 64);
        d += __shfl_xor(d, 2, 64);
        d += __shfl_xor(d, 4, 64);
        d += __shfl_xor(d, 8, 64);
        const float x  = cd[j] * d;
        const float ls = fminf(x, 0.f) - __logf(1.f + __expf(-fabsf(x)));
        acc = fmaf(fabsf(cd[j]), ls, acc);
    }

    // sum across the 4 groups
    acc += __shfl_xor(acc, 16, 64);
    acc += __shfl_xor(acc, 32, 64);

    if (lane == 0) ws[wave] = -acc;
    __syncthreads();
    if (threadIdx.x == 0) {
        partials[blockIdx.x] = ws[0] + ws[1] + ws[2] + ws[3];
    }
}

__global__ __launch_bounds__(256) void hs_reduce_kernel(
    const float* __restrict__ partials, float* __restrict__ out)
{
    const float4* p4 = (const float4*)partials;     // 2048 float4
    float s = 0.f;
    #pragma unroll
    for (int i = 0; i < NBLOCKS / 4 / 256; ++i) {
        const float4 v = p4[i * 256 + threadIdx.x];
        s += (v.x + v.y) + (v.z + v.w);
    }
    #pragma unroll
    for (int off = 32; off; off >>= 1) s += __shfl_xor(s, off, 64);
    __shared__ float ws[4];
    const int wave = threadIdx.x >> 6;
    const int lane = threadIdx.x & 63;
    if (lane == 0) ws[wave] = s;
    __syncthreads();
    if (threadIdx.x == 0) {
        out[0] = (ws[0] + ws[1] + ws[2] + ws[3]) / (float)BATCH;
    }
}

extern "C" void kernel_launch(void* const* d_in, const int* in_sizes, int n_in,
                              void* d_out, int out_size, void* d_ws, size_t ws_size,
                              hipStream_t stream) {
    const int*   center    = (const int*)d_in[0];
    const int*   target    = (const int*)d_in[1];
    const float* in_emb    = (const float*)d_in[2];
    const float* inner_vec = (const float*)d_in[3];
    const int*   paths     = (const int*)d_in[4];
    const float* codes     = (const float*)d_in[5];
    // d_in[6] (masks) intentionally unused: mask == |code|
    float* out = (float*)d_out;
    float* partials = (float*)d_ws;   // 8192 floats = 32 KB scratch

    hs_loss_kernel<<<NBLOCKS, 256, 0, stream>>>(
        center, target, in_emb, inner_vec, paths, codes, partials);
    hs_reduce_kernel<<<1, 256, 0, stream>>>(partials, out);
}